// Round 9
// baseline (432.316 us; speedup 1.0000x reference)
//
#include <hip/hip_runtime.h>
#include <math.h>

#define BLK 256
#define SCAN_CHUNK 1024
// bucketed CSR build: 512 dst-nodes per bucket
#define BKT_BITS 9
#define BKT (1<<BKT_BITS)
#define MAXNB 256
#define EB 8192   // edges per bin-block

typedef __attribute__((ext_vector_type(8))) short bf16x8;
typedef __attribute__((ext_vector_type(4))) float f32x4;

__device__ inline unsigned short f2b(float f){
  union { float f; unsigned int u; } v; v.f = f;
  unsigned int u = v.u;
  return (unsigned short)((u + 0x7FFF + ((u >> 16) & 1)) >> 16);
}
__device__ inline float b2f_lo(unsigned int u){
  union { unsigned int u; float f; } v; v.u = u << 16; return v.f;
}
__device__ inline float b2f_hi(unsigned int u){
  union { unsigned int u; float f; } v; v.u = u & 0xFFFF0000u; return v.f;
}

// ---------------- CSR build (9-dispatch pipeline) ----------------

// bucket histogram (LDS) + per-node degree (global atomics) in one pass
__global__ __launch_bounds__(256)
void bhistA(const int* __restrict__ dst, int* __restrict__ bhist,
            int* __restrict__ deg, int E, int NB){
  __shared__ int h[MAXNB];
  int t = threadIdx.x;
  for (int i=t;i<NB;i+=256) h[i]=0;
  __syncthreads();
  int base = blockIdx.x*EB;
  #pragma unroll
  for (int k=0;k<EB/256;k++){
    int idx = base + k*256 + t;
    if (idx < E){
      int d = dst[idx];
      atomicAdd(&h[d>>BKT_BITS], 1);
      atomicAdd(&deg[d], 1);
    }
  }
  __syncthreads();
  for (int i=t;i<NB;i+=256) if (h[i]) atomicAdd(&bhist[i], h[i]);
}

// bin edges into buckets via LDS sort; packed 4B output (src<<9 | dst&511)
// bucket offsets computed redundantly per block from bhist (no bscanB dispatch)
__global__ __launch_bounds__(256)
void binC(const int* __restrict__ src, const int* __restrict__ dst,
          const int* __restrict__ bhist, int* __restrict__ bcur,
          unsigned int* __restrict__ bins, int E, int NB){
  __shared__ int hsc[MAXNB];
  __shared__ int lh[MAXNB];
  __shared__ int lofs[MAXNB];
  __shared__ int lcur[MAXNB];
  __shared__ int gres[MAXNB];
  __shared__ __attribute__((aligned(16))) int2 buf[EB];
  int t = threadIdx.x;
  // local exclusive scan of bhist -> bucket base offsets
  int v0 = (t < NB) ? bhist[t] : 0;
  hsc[t] = v0;
  for (int i=t;i<NB;i+=256) lh[i]=0;
  __syncthreads();
  for (int off=1; off<MAXNB; off<<=1){
    int v = (t>=off)?hsc[t-off]:0;
    __syncthreads();
    hsc[t]+=v;
    __syncthreads();
  }
  int boff_t = hsc[t]-v0;
  int base = blockIdx.x*EB;
  #pragma unroll
  for (int k=0;k<EB/256;k++){
    int idx = base + k*256 + t;
    if (idx < E) atomicAdd(&lh[dst[idx]>>BKT_BITS], 1);
  }
  __syncthreads();
  if (t==0){ int run=0; for (int b=0;b<NB;b++){ lofs[b]=run; run+=lh[b]; } }
  __syncthreads();
  if (t<NB){
    lcur[t] = lofs[t];
    gres[t] = lh[t] ? (boff_t + atomicAdd(&bcur[t], lh[t])) : 0;
  }
  __syncthreads();
  #pragma unroll
  for (int k=0;k<EB/256;k++){
    int idx = base + k*256 + t;
    if (idx < E){
      int d = dst[idx];
      int p = atomicAdd(&lcur[d>>BKT_BITS], 1);
      buf[p] = make_int2(src[idx], d);
    }
  }
  __syncthreads();
  int total = E - base; if (total > EB) total = EB;
  for (int i=t; i<total; i+=256){
    int2 pr = buf[i];
    int b = pr.y>>BKT_BITS;
    bins[gres[b] + (i - lofs[b])] = ((unsigned)pr.x << BKT_BITS) | (unsigned)(pr.y & (BKT-1));
  }
}

// single-kernel scan: local scan + parallel decoupled posts (O(1) depth, not a chain)
// + dinv fused + W1 transpose/cvt tail blocks
__global__ __launch_bounds__(256)
void scan_one(const int* __restrict__ deg, int* __restrict__ rowptr,
              int* __restrict__ bsum, float* __restrict__ dinv,
              const float* __restrict__ W1, unsigned short* __restrict__ W1T,
              int N, int SB){
  int b = blockIdx.x;
  if (b >= SB){   // W1 transpose+cvt tail
    int t = (b - SB)*256 + threadIdx.x;
    if (t < 256*128){
      int k = t >> 7, n = t & 127;
      W1T[n*256 + k] = f2b(W1[t]);
    }
    return;
  }
  __shared__ int sd[BLK];
  __shared__ int sbase;
  int tid = threadIdx.x;
  int base = b * SCAN_CHUNK;
  int vals[4]; int tsum = 0;
  #pragma unroll
  for (int q=0;q<4;q++){
    int idx = base + tid*4 + q;
    int v = 0;
    if (idx < N){
      int dg = deg[idx];
      v = dg + 1;                       // +1 self-loop
      dinv[idx] = rsqrtf((float)(dg + 1));
    }
    vals[q] = v; tsum += v;
  }
  sd[tid] = tsum;
  if (tid == 0) sbase = 0;
  __syncthreads();
  for (int off=1; off<BLK; off<<=1){
    int v = (tid >= off) ? sd[tid-off] : 0;
    __syncthreads();
    sd[tid] += v;
    __syncthreads();
  }
  // post local total (release) BEFORE waiting on anyone
  if (tid == 0)
    __hip_atomic_store(&bsum[b], sd[BLK-1] + 1, __ATOMIC_RELEASE, __HIP_MEMORY_SCOPE_AGENT);
  // parallel spin: each thread owns <=1 predecessor (b<=97 < 256)
  int part = 0;
  for (int j = tid; j < b; j += 256){
    int v;
    do { v = __hip_atomic_load(&bsum[j], __ATOMIC_ACQUIRE, __HIP_MEMORY_SCOPE_AGENT); } while (v == 0);
    part += v - 1;
  }
  if (part) atomicAdd(&sbase, part);
  __syncthreads();
  int gbase = sbase;
  if (b == 0 && tid == 0) rowptr[0] = 0;
  int run = sd[tid] - tsum;
  #pragma unroll
  for (int q=0;q<4;q++){
    run += vals[q];
    int idx = base + tid*4 + q;
    if (idx < N) rowptr[idx+1] = gbase + run;
  }
}

// per-bucket CSR fill — bucket base via local reduction of bhist[0..b)
__global__ __launch_bounds__(256)
void bfillF(const unsigned int* __restrict__ bins, const int* __restrict__ bhist,
            const int* __restrict__ rowptr, int* __restrict__ col, int N){
  __shared__ int rp[BKT];
  __shared__ int cur[BKT];
  __shared__ int srp;
  int b = blockIdx.x;
  int base = b<<BKT_BITS;
  int partial = 0;
  for (int j=threadIdx.x; j<b; j+=256) partial += bhist[j];
  if (threadIdx.x==0) srp = 0;
  for (int i=threadIdx.x;i<BKT;i+=256){
    int node = base+i;
    rp[i] = (node < N) ? rowptr[node] : 0;
    cur[i] = 0;
  }
  __syncthreads();
  if (partial) atomicAdd(&srp, partial);
  __syncthreads();
  int s = srp, cnt = bhist[b];
  for (int i=threadIdx.x;i<cnt;i+=256){
    unsigned pk = bins[s+i];
    int ln = pk & (BKT-1);
    int slot = atomicAdd(&cur[ln], 1);
    col[rp[ln] + slot] = (int)(pk >> BKT_BITS);
  }
  __syncthreads();
  for (int i=threadIdx.x;i<BKT;i+=256){
    int node = base+i;
    if (node < N) col[rp[i] + cur[i]] = node;   // self-loop last
  }
}

// ---------------- GEMM1 (MFMA bf16): h1b[r] = dinv[r] * (x @ W1)[r], bf16 ----------------

#define XPAD 40

__global__ __launch_bounds__(256)
void gemm1_mfma(const float* __restrict__ X, const unsigned short* __restrict__ W1T,
                const float* __restrict__ dinv, unsigned short* __restrict__ H1B, int M){
  __shared__ __attribute__((aligned(16))) unsigned short xs[128*XPAD];
  __shared__ __attribute__((aligned(16))) unsigned short wt[128*XPAD];
  const int tid = threadIdx.x;
  const int wave = tid >> 6, lane = tid & 63;
  const int quad = lane >> 4, l16 = lane & 15;
  const int row0 = blockIdx.x * 128;

  f32x4 acc[2][8];
  #pragma unroll
  for (int i=0;i<2;i++)
    #pragma unroll
    for (int j=0;j<8;j++) acc[i][j] = (f32x4){0.f,0.f,0.f,0.f};

  const int r    = tid >> 1;
  const int half = tid & 1;

  for (int k0 = 0; k0 < 256; k0 += 32){
    {
      int gr = row0 + r;
      const float* xp = X + (size_t)gr*256 + k0 + half*16;
      unsigned short* xd = xs + r*XPAD + half*16;
      #pragma unroll
      for (int q=0;q<4;q++){
        float4 v = (gr < M) ? *(const float4*)(xp + q*4) : make_float4(0.f,0.f,0.f,0.f);
        ushort4 b;
        b.x = f2b(v.x); b.y = f2b(v.y); b.z = f2b(v.z); b.w = f2b(v.w);
        *(ushort4*)(xd + q*4) = b;
      }
    }
    {
      const unsigned short* wp = W1T + r*256 + k0 + half*16;
      unsigned short* wd = wt + r*XPAD + half*16;
      uint4 a = *(const uint4*)wp;
      uint4 c = *(const uint4*)(wp + 8);
      *(uint4*)wd = a;
      *(uint4*)(wd + 8) = c;
    }
    __syncthreads();

    bf16x8 bfr[8];
    #pragma unroll
    for (int ct=0; ct<8; ct++)
      bfr[ct] = *(bf16x8*)(wt + (ct*16 + l16)*XPAD + quad*8);
    #pragma unroll
    for (int rt=0; rt<2; rt++){
      bf16x8 a = *(bf16x8*)(xs + (wave*32 + rt*16 + l16)*XPAD + quad*8);
      #pragma unroll
      for (int ct=0; ct<8; ct++)
        acc[rt][ct] = __builtin_amdgcn_mfma_f32_16x16x32_bf16(a, bfr[ct], acc[rt][ct], 0, 0, 0);
    }
    __syncthreads();
  }

  #pragma unroll
  for (int rt=0; rt<2; rt++){
    int rbase = row0 + wave*32 + rt*16 + quad*4;
    #pragma unroll
    for (int rg=0; rg<4; rg++){
      int grow = rbase + rg;
      if (grow < M){
        float dv = dinv[grow];
        #pragma unroll
        for (int ct=0; ct<8; ct++)
          H1B[(size_t)grow*128 + ct*16 + l16] = f2b(dv * acc[rt][ct][rg]);
      }
    }
  }
}

// ---------------- agg1: wave/node gather (8-wide) + dinv + bias + ReLU -> bf16 r1 ----------------

__global__ __launch_bounds__(256)
void agg1_kernel(const unsigned short* __restrict__ H1B, const int* __restrict__ rowptr,
                 const int* __restrict__ col, const float* __restrict__ dinv,
                 const float* __restrict__ b1, unsigned int* __restrict__ R1B, int N){
  int node = blockIdx.x * 4 + (threadIdx.x >> 6);
  int lane = threadIdx.x & 63;
  if (node >= N) return;
  int s = rowptr[node], e = rowptr[node+1];
  float aL[8], aH[8];
  #pragma unroll
  for (int k=0;k<8;k++){ aL[k]=0.f; aH[k]=0.f; }
  int j = s;
  for (; j+7 < e; j += 8){
    unsigned u[8];
    #pragma unroll
    for (int k=0;k<8;k++)
      u[k] = *(const unsigned*)(H1B + (size_t)col[j+k]*128 + lane*2);
    #pragma unroll
    for (int k=0;k<8;k++){ aL[k] += b2f_lo(u[k]); aH[k] += b2f_hi(u[k]); }
  }
  for (; j < e; j++){
    unsigned u0 = *(const unsigned*)(H1B + (size_t)col[j]*128 + lane*2);
    aL[0] += b2f_lo(u0); aH[0] += b2f_hi(u0);
  }
  float acc0 = ((aL[0]+aL[1])+(aL[2]+aL[3])) + ((aL[4]+aL[5])+(aL[6]+aL[7]));
  float acc1 = ((aH[0]+aH[1])+(aH[2]+aH[3])) + ((aH[4]+aH[5])+(aH[6]+aH[7]));
  float dv = dinv[node];
  float r0 = fmaxf(dv*acc0 + b1[lane*2],     0.f);
  float r1 = fmaxf(dv*acc1 + b1[lane*2 + 1], 0.f);
  R1B[(size_t)node*64 + lane] = (unsigned)f2b(r0) | ((unsigned)f2b(r1) << 16);
}

// ---------------- GEMM2: h2b[r] = bf16( dinv[r] * (r1[r] @ W2) ), packed 32B stride ----------------

__global__ __launch_bounds__(256)
void gemm2_kernel(const unsigned int* __restrict__ R1B, const float* __restrict__ W2,
                  const float* __restrict__ dinv, unsigned int* __restrict__ H2B, int M){
  __shared__ float w2s[128*10];
  for (int i = threadIdx.x; i < 128*10; i += blockDim.x) w2s[i] = W2[i];
  __syncthreads();
  int r = blockIdx.x*blockDim.x + threadIdx.x;
  if (r >= M) return;
  float acc[10];
  #pragma unroll
  for (int c=0;c<10;c++) acc[c] = 0.f;
  const unsigned int* row = R1B + (size_t)r*64;
  for (int k=0;k<64;k+=4){
    uint4 u = *(const uint4*)(row + k);
    float f0 = b2f_lo(u.x), f1 = b2f_hi(u.x);
    float f2 = b2f_lo(u.y), f3 = b2f_hi(u.y);
    float f4 = b2f_lo(u.z), f5 = b2f_hi(u.z);
    float f6 = b2f_lo(u.w), f7 = b2f_hi(u.w);
    #pragma unroll
    for (int c=0;c<10;c++){
      acc[c] += f0*w2s[(2*k+0)*10+c] + f1*w2s[(2*k+1)*10+c]
              + f2*w2s[(2*k+2)*10+c] + f3*w2s[(2*k+3)*10+c]
              + f4*w2s[(2*k+4)*10+c] + f5*w2s[(2*k+5)*10+c]
              + f6*w2s[(2*k+6)*10+c] + f7*w2s[(2*k+7)*10+c];
    }
  }
  float dv = dinv[r];
  unsigned int p[5];
  #pragma unroll
  for (int c=0;c<5;c++)
    p[c] = (unsigned)f2b(dv*acc[2*c]) | ((unsigned)f2b(dv*acc[2*c+1]) << 16);
  unsigned int* op = H2B + (size_t)r*8;
  *(uint4*)op = make_uint4(p[0],p[1],p[2],p[3]);
  op[4] = p[4];
}

// ---------------- agg2 + bias + log_softmax (2-wide, bf16 h2) ----------------

__global__ __launch_bounds__(256)
void agg2_softmax_kernel(const unsigned int* __restrict__ H2B, const int* __restrict__ rowptr,
                         const int* __restrict__ col, const float* __restrict__ dinv,
                         const float* __restrict__ b2, float* __restrict__ out, int N){
  int i = blockIdx.x*blockDim.x + threadIdx.x;
  if (i >= N) return;
  float acc[10], acc2[10];
  #pragma unroll
  for (int c=0;c<10;c++){ acc[c] = 0.f; acc2[c] = 0.f; }
  int s = rowptr[i], e = rowptr[i+1];
  int j = s;
  for (; j+1 < e; j += 2){
    const unsigned int* hA = H2B + (size_t)col[j]*8;
    const unsigned int* hB = H2B + (size_t)col[j+1]*8;
    uint4 a = *(const uint4*)hA; unsigned a4 = hA[4];
    uint4 b = *(const uint4*)hB; unsigned b4 = hB[4];
    acc[0]+=b2f_lo(a.x); acc[1]+=b2f_hi(a.x); acc[2]+=b2f_lo(a.y); acc[3]+=b2f_hi(a.y);
    acc[4]+=b2f_lo(a.z); acc[5]+=b2f_hi(a.z); acc[6]+=b2f_lo(a.w); acc[7]+=b2f_hi(a.w);
    acc[8]+=b2f_lo(a4);  acc[9]+=b2f_hi(a4);
    acc2[0]+=b2f_lo(b.x); acc2[1]+=b2f_hi(b.x); acc2[2]+=b2f_lo(b.y); acc2[3]+=b2f_hi(b.y);
    acc2[4]+=b2f_lo(b.z); acc2[5]+=b2f_hi(b.z); acc2[6]+=b2f_lo(b.w); acc2[7]+=b2f_hi(b.w);
    acc2[8]+=b2f_lo(b4);  acc2[9]+=b2f_hi(b4);
  }
  if (j < e){
    const unsigned int* hA = H2B + (size_t)col[j]*8;
    uint4 a = *(const uint4*)hA; unsigned a4 = hA[4];
    acc[0]+=b2f_lo(a.x); acc[1]+=b2f_hi(a.x); acc[2]+=b2f_lo(a.y); acc[3]+=b2f_hi(a.y);
    acc[4]+=b2f_lo(a.z); acc[5]+=b2f_hi(a.z); acc[6]+=b2f_lo(a.w); acc[7]+=b2f_hi(a.w);
    acc[8]+=b2f_lo(a4);  acc[9]+=b2f_hi(a4);
  }
  float dv = dinv[i];
  #pragma unroll
  for (int f=0;f<10;f++) acc[f] = dv*(acc[f] + acc2[f]) + b2[f];
  float m = acc[0];
  #pragma unroll
  for (int f=1;f<10;f++) m = fmaxf(m, acc[f]);
  float sum = 0.f;
  #pragma unroll
  for (int f=0;f<10;f++) sum += expf(acc[f] - m);
  float lg = m + logf(sum);
  #pragma unroll
  for (int f=0;f<10;f++) out[(size_t)i*10 + f] = acc[f] - lg;
}

// ---------------- launch ----------------

extern "C" void kernel_launch(void* const* d_in, const int* in_sizes, int n_in,
                              void* d_out, int out_size, void* d_ws, size_t ws_size,
                              hipStream_t stream){
  const float* x    = (const float*)d_in[0];
  const int*   ei   = (const int*)d_in[1];
  const float* W1   = (const float*)d_in[2];
  const float* b1   = (const float*)d_in[3];
  const float* W2   = (const float*)d_in[4];
  const float* b2   = (const float*)d_in[5];
  float* out = (float*)d_out;

  const int N = in_sizes[0] / 256;   // 100000
  const int E = in_sizes[1] / 2;     // 1600000
  const int NNZ = E + N;
  const int* src = ei;
  const int* dst = ei + E;
  const int NB = (N + BKT - 1) >> BKT_BITS;          // 196
  const int SB = (N + SCAN_CHUNK - 1) / SCAN_CHUNK;  // 98 scan blocks
  const int WB = 128;                                // wcvt tail blocks

  char* ws = (char*)d_ws;
  size_t off = 0;
  auto alloc = [&](size_t bytes)->char*{
    char* p = ws + off;
    off = (off + bytes + 255) & ~(size_t)255;
    return p;
  };
  // zero region: bhist | bcur | bsum | deg  (single memset)
  int*   zreg   = (int*)  alloc((size_t)(MAXNB*3 + N)*4);
  int*   bhist  = zreg;
  int*   bcur   = zreg + MAXNB;
  int*   bsum   = zreg + MAXNB*2;
  int*   deg    = zreg + MAXNB*3;
  float* dinv   = (float*)alloc((size_t)N*4);
  int*   rowptr = (int*)  alloc((size_t)(N+1)*4);
  unsigned int* bins = (unsigned int*)alloc((size_t)E*4);
  int*   col    = (int*)  alloc((size_t)NNZ*4);
  unsigned short* w1t = (unsigned short*)alloc((size_t)128*256*2);
  unsigned short* h1b = (unsigned short*)alloc((size_t)N*128*2);
  unsigned int*   r1b = (unsigned int*)  alloc((size_t)N*64*4);
  unsigned int*   h2b = (unsigned int*)  alloc((size_t)N*8*4);
  (void)ws_size;

  hipMemsetAsync(zreg, 0, (size_t)(MAXNB*3 + N)*4, stream);

  const int NCB = (E + EB - 1) / EB;

  bhistA<<<NCB, 256, 0, stream>>>(dst, bhist, deg, E, NB);
  binC<<<NCB, 256, 0, stream>>>(src, dst, bhist, bcur, bins, E, NB);
  scan_one<<<SB + WB, 256, 0, stream>>>(deg, rowptr, bsum, dinv, W1, w1t, N, SB);
  bfillF<<<NB, 256, 0, stream>>>(bins, bhist, rowptr, col, N);

  gemm1_mfma<<<(N+127)/128, 256, 0, stream>>>(x, w1t, dinv, h1b, N);
  agg1_kernel<<<(N+3)/4, 256, 0, stream>>>(h1b, rowptr, col, dinv, b1, r1b, N);
  gemm2_kernel<<<(N+BLK-1)/BLK, BLK, 0, stream>>>(r1b, W2, dinv, h2b, N);
  agg2_softmax_kernel<<<(N+BLK-1)/BLK, BLK, 0, stream>>>(h2b, rowptr, col, dinv, b2, out, N);
}

// Round 10
// 378.239 us; speedup vs baseline: 1.1430x; 1.1430x over previous
//
#include <hip/hip_runtime.h>
#include <math.h>

#define BLK 256
// bucketed CSR build: 512 dst-nodes per bucket
#define BKT_BITS 9
#define BKT (1<<BKT_BITS)
#define MAXNB 256
#define EB 8192   // edges per bin-block

typedef __attribute__((ext_vector_type(8))) short bf16x8;
typedef __attribute__((ext_vector_type(4))) float f32x4;

__device__ inline unsigned short f2b(float f){
  union { float f; unsigned int u; } v; v.f = f;
  unsigned int u = v.u;
  return (unsigned short)((u + 0x7FFF + ((u >> 16) & 1)) >> 16);
}
__device__ inline float b2f_lo(unsigned int u){
  union { unsigned int u; float f; } v; v.u = u << 16; return v.f;
}
__device__ inline float b2f_hi(unsigned int u){
  union { unsigned int u; float f; } v; v.u = u & 0xFFFF0000u; return v.f;
}

// ---------------- CSR build (3 kernels) ----------------

// bucket histogram only — LDS atomics + ~196 global adds per block
__global__ __launch_bounds__(256)
void bhistA(const int* __restrict__ dst, int* __restrict__ bhist, int E, int NB){
  __shared__ int h[MAXNB];
  int t = threadIdx.x;
  for (int i=t;i<NB;i+=256) h[i]=0;
  __syncthreads();
  int base = blockIdx.x*EB;
  #pragma unroll
  for (int k=0;k<EB/256;k++){
    int idx = base + k*256 + t;
    if (idx < E) atomicAdd(&h[dst[idx]>>BKT_BITS], 1);
  }
  __syncthreads();
  for (int i=t;i<NB;i+=256) if (h[i]) atomicAdd(&bhist[i], h[i]);
}

// bin edges into buckets via LDS sort; packed 4B output (src<<9 | dst&511)
// bucket base offsets computed redundantly per block from bhist
__global__ __launch_bounds__(256)
void binC(const int* __restrict__ src, const int* __restrict__ dst,
          const int* __restrict__ bhist, int* __restrict__ bcur,
          unsigned int* __restrict__ bins, int E, int NB){
  __shared__ int hsc[MAXNB];
  __shared__ int lh[MAXNB];
  __shared__ int lofs[MAXNB];
  __shared__ int lcur[MAXNB];
  __shared__ int gres[MAXNB];
  __shared__ __attribute__((aligned(16))) int2 buf[EB];
  int t = threadIdx.x;
  int v0 = (t < NB) ? bhist[t] : 0;
  hsc[t] = v0;
  for (int i=t;i<NB;i+=256) lh[i]=0;
  __syncthreads();
  for (int off=1; off<MAXNB; off<<=1){
    int v = (t>=off)?hsc[t-off]:0;
    __syncthreads();
    hsc[t]+=v;
    __syncthreads();
  }
  int boff_t = hsc[t]-v0;
  int base = blockIdx.x*EB;
  #pragma unroll
  for (int k=0;k<EB/256;k++){
    int idx = base + k*256 + t;
    if (idx < E) atomicAdd(&lh[dst[idx]>>BKT_BITS], 1);
  }
  __syncthreads();
  if (t==0){ int run=0; for (int b=0;b<NB;b++){ lofs[b]=run; run+=lh[b]; } }
  __syncthreads();
  if (t<NB){
    lcur[t] = lofs[t];
    gres[t] = lh[t] ? (boff_t + atomicAdd(&bcur[t], lh[t])) : 0;
  }
  __syncthreads();
  #pragma unroll
  for (int k=0;k<EB/256;k++){
    int idx = base + k*256 + t;
    if (idx < E){
      int d = dst[idx];
      int p = atomicAdd(&lcur[d>>BKT_BITS], 1);
      buf[p] = make_int2(src[idx], d);
    }
  }
  __syncthreads();
  int total = E - base; if (total > EB) total = EB;
  for (int i=t; i<total; i+=256){
    int2 pr = buf[i];
    int b = pr.y>>BKT_BITS;
    bins[gres[b] + (i - lofs[b])] = ((unsigned)pr.x << BKT_BITS) | (unsigned)(pr.y & (BKT-1));
  }
}

// per-bucket: degree (LDS atomics) -> local 512-scan -> rowptr + dinv + col fill + self-loops.
// No global scan: rowptr[node] = sum(bhist[0..b)) + base + local_excl_scan(dcnt+1).
// W1 transpose/cvt as independent tail blocks.
__global__ __launch_bounds__(256)
void bfill_all(const unsigned int* __restrict__ bins, const int* __restrict__ bhist,
               int* __restrict__ rowptr, float* __restrict__ dinv, int* __restrict__ col,
               const float* __restrict__ W1, unsigned short* __restrict__ W1T,
               int N, int NB){
  int b = blockIdx.x;
  if (b >= NB){   // W1 transpose+cvt tail
    int t2 = (b - NB)*256 + threadIdx.x;
    if (t2 < 256*128){
      int k = t2 >> 7, n = t2 & 127;
      W1T[n*256 + k] = f2b(W1[t2]);
    }
    return;
  }
  __shared__ int dcnt[BKT];
  __shared__ int rp[BKT];
  __shared__ int cur[BKT];
  __shared__ int sscan[256];
  __shared__ int sboff;
  int t = threadIdx.x;
  // bucket edge base = sum bhist[0..b)  (parallel partial + LDS reduce)
  int partial = 0;
  for (int j=t; j<b; j+=256) partial += bhist[j];
  if (t==0) sboff = 0;
  dcnt[t] = 0; dcnt[t+256] = 0;
  __syncthreads();
  if (partial) atomicAdd(&sboff, partial);
  __syncthreads();
  int s = sboff, cnt = bhist[b];
  // degree count from bucket's bin run
  for (int i=t;i<cnt;i+=256) atomicAdd(&dcnt[bins[s+i] & (BKT-1)], 1);
  __syncthreads();
  // local exclusive scan of (deg+1) over 512 nodes (2/thread)
  int base = b<<BKT_BITS;
  int i0 = 2*t, i1 = 2*t+1;
  int d0 = dcnt[i0], d1 = dcnt[i1];
  int n0 = (base+i0 < N) ? d0+1 : 0;
  int n1 = (base+i1 < N) ? d1+1 : 0;
  int tsum = n0+n1;
  sscan[t] = tsum; __syncthreads();
  for (int off=1; off<256; off<<=1){
    int v = (t>=off)? sscan[t-off]:0;
    __syncthreads();
    sscan[t]+=v;
    __syncthreads();
  }
  int run = sscan[t]-tsum;
  int gstart = s + base;   // prior buckets: s edges + base self-loops
  int rp0 = gstart + run, rp1 = rp0 + n0;
  rp[i0] = rp0; rp[i1] = rp1;
  cur[i0] = 0;  cur[i1] = 0;
  if (base+i0 < N){
    rowptr[base+i0] = rp0;
    dinv[base+i0] = rsqrtf((float)(d0+1));
    if (base+i0 == N-1) rowptr[N] = rp0 + d0 + 1;
  }
  if (base+i1 < N){
    rowptr[base+i1] = rp1;
    dinv[base+i1] = rsqrtf((float)(d1+1));
    if (base+i1 == N-1) rowptr[N] = rp1 + d1 + 1;
  }
  __syncthreads();
  // fill col via LDS cursors (single-CU full-line writes)
  for (int i=t;i<cnt;i+=256){
    unsigned pk = bins[s+i];
    int ln = pk & (BKT-1);
    int slot = atomicAdd(&cur[ln], 1);
    col[rp[ln] + slot] = (int)(pk >> BKT_BITS);
  }
  __syncthreads();
  for (int i=t;i<BKT;i+=256){
    int node = base+i;
    if (node < N) col[rp[i] + dcnt[i]] = node;   // self-loop last
  }
}

// ---------------- GEMM1 (MFMA bf16): h1b[r] = dinv[r] * (x @ W1)[r], bf16 ----------------

#define XPAD 40

__global__ __launch_bounds__(256)
void gemm1_mfma(const float* __restrict__ X, const unsigned short* __restrict__ W1T,
                const float* __restrict__ dinv, unsigned short* __restrict__ H1B, int M){
  __shared__ __attribute__((aligned(16))) unsigned short xs[128*XPAD];
  __shared__ __attribute__((aligned(16))) unsigned short wt[128*XPAD];
  const int tid = threadIdx.x;
  const int wave = tid >> 6, lane = tid & 63;
  const int quad = lane >> 4, l16 = lane & 15;
  const int row0 = blockIdx.x * 128;

  f32x4 acc[2][8];
  #pragma unroll
  for (int i=0;i<2;i++)
    #pragma unroll
    for (int j=0;j<8;j++) acc[i][j] = (f32x4){0.f,0.f,0.f,0.f};

  const int r    = tid >> 1;
  const int half = tid & 1;

  for (int k0 = 0; k0 < 256; k0 += 32){
    {
      int gr = row0 + r;
      const float* xp = X + (size_t)gr*256 + k0 + half*16;
      unsigned short* xd = xs + r*XPAD + half*16;
      #pragma unroll
      for (int q=0;q<4;q++){
        float4 v = (gr < M) ? *(const float4*)(xp + q*4) : make_float4(0.f,0.f,0.f,0.f);
        ushort4 b;
        b.x = f2b(v.x); b.y = f2b(v.y); b.z = f2b(v.z); b.w = f2b(v.w);
        *(ushort4*)(xd + q*4) = b;
      }
    }
    {
      const unsigned short* wp = W1T + r*256 + k0 + half*16;
      unsigned short* wd = wt + r*XPAD + half*16;
      uint4 a = *(const uint4*)wp;
      uint4 c = *(const uint4*)(wp + 8);
      *(uint4*)wd = a;
      *(uint4*)(wd + 8) = c;
    }
    __syncthreads();

    bf16x8 bfr[8];
    #pragma unroll
    for (int ct=0; ct<8; ct++)
      bfr[ct] = *(bf16x8*)(wt + (ct*16 + l16)*XPAD + quad*8);
    #pragma unroll
    for (int rt=0; rt<2; rt++){
      bf16x8 a = *(bf16x8*)(xs + (wave*32 + rt*16 + l16)*XPAD + quad*8);
      #pragma unroll
      for (int ct=0; ct<8; ct++)
        acc[rt][ct] = __builtin_amdgcn_mfma_f32_16x16x32_bf16(a, bfr[ct], acc[rt][ct], 0, 0, 0);
    }
    __syncthreads();
  }

  #pragma unroll
  for (int rt=0; rt<2; rt++){
    int rbase = row0 + wave*32 + rt*16 + quad*4;
    #pragma unroll
    for (int rg=0; rg<4; rg++){
      int grow = rbase + rg;
      if (grow < M){
        float dv = dinv[grow];
        #pragma unroll
        for (int ct=0; ct<8; ct++)
          H1B[(size_t)grow*128 + ct*16 + l16] = f2b(dv * acc[rt][ct][rg]);
      }
    }
  }
}

// ---------------- agg1: wave/node gather (8-wide) + dinv + bias + ReLU -> bf16 r1 ----------------

__global__ __launch_bounds__(256)
void agg1_kernel(const unsigned short* __restrict__ H1B, const int* __restrict__ rowptr,
                 const int* __restrict__ col, const float* __restrict__ dinv,
                 const float* __restrict__ b1, unsigned int* __restrict__ R1B, int N){
  int node = blockIdx.x * 4 + (threadIdx.x >> 6);
  int lane = threadIdx.x & 63;
  if (node >= N) return;
  int s = rowptr[node], e = rowptr[node+1];
  float aL[8], aH[8];
  #pragma unroll
  for (int k=0;k<8;k++){ aL[k]=0.f; aH[k]=0.f; }
  int j = s;
  for (; j+7 < e; j += 8){
    unsigned u[8];
    #pragma unroll
    for (int k=0;k<8;k++)
      u[k] = *(const unsigned*)(H1B + (size_t)col[j+k]*128 + lane*2);
    #pragma unroll
    for (int k=0;k<8;k++){ aL[k] += b2f_lo(u[k]); aH[k] += b2f_hi(u[k]); }
  }
  for (; j < e; j++){
    unsigned u0 = *(const unsigned*)(H1B + (size_t)col[j]*128 + lane*2);
    aL[0] += b2f_lo(u0); aH[0] += b2f_hi(u0);
  }
  float acc0 = ((aL[0]+aL[1])+(aL[2]+aL[3])) + ((aL[4]+aL[5])+(aL[6]+aL[7]));
  float acc1 = ((aH[0]+aH[1])+(aH[2]+aH[3])) + ((aH[4]+aH[5])+(aH[6]+aH[7]));
  float dv = dinv[node];
  float r0 = fmaxf(dv*acc0 + b1[lane*2],     0.f);
  float r1 = fmaxf(dv*acc1 + b1[lane*2 + 1], 0.f);
  R1B[(size_t)node*64 + lane] = (unsigned)f2b(r0) | ((unsigned)f2b(r1) << 16);
}

// ---------------- GEMM2: h2b[r] = bf16( dinv[r] * (r1[r] @ W2) ), packed 32B stride ----------------

__global__ __launch_bounds__(256)
void gemm2_kernel(const unsigned int* __restrict__ R1B, const float* __restrict__ W2,
                  const float* __restrict__ dinv, unsigned int* __restrict__ H2B, int M){
  __shared__ float w2s[128*10];
  for (int i = threadIdx.x; i < 128*10; i += blockDim.x) w2s[i] = W2[i];
  __syncthreads();
  int r = blockIdx.x*blockDim.x + threadIdx.x;
  if (r >= M) return;
  float acc[10];
  #pragma unroll
  for (int c=0;c<10;c++) acc[c] = 0.f;
  const unsigned int* row = R1B + (size_t)r*64;
  for (int k=0;k<64;k+=4){
    uint4 u = *(const uint4*)(row + k);
    float f0 = b2f_lo(u.x), f1 = b2f_hi(u.x);
    float f2 = b2f_lo(u.y), f3 = b2f_hi(u.y);
    float f4 = b2f_lo(u.z), f5 = b2f_hi(u.z);
    float f6 = b2f_lo(u.w), f7 = b2f_hi(u.w);
    #pragma unroll
    for (int c=0;c<10;c++){
      acc[c] += f0*w2s[(2*k+0)*10+c] + f1*w2s[(2*k+1)*10+c]
              + f2*w2s[(2*k+2)*10+c] + f3*w2s[(2*k+3)*10+c]
              + f4*w2s[(2*k+4)*10+c] + f5*w2s[(2*k+5)*10+c]
              + f6*w2s[(2*k+6)*10+c] + f7*w2s[(2*k+7)*10+c];
    }
  }
  float dv = dinv[r];
  unsigned int p[5];
  #pragma unroll
  for (int c=0;c<5;c++)
    p[c] = (unsigned)f2b(dv*acc[2*c]) | ((unsigned)f2b(dv*acc[2*c+1]) << 16);
  unsigned int* op = H2B + (size_t)r*8;
  *(uint4*)op = make_uint4(p[0],p[1],p[2],p[3]);
  op[4] = p[4];
}

// ---------------- agg2 + bias + log_softmax (2-wide, bf16 h2) ----------------

__global__ __launch_bounds__(256)
void agg2_softmax_kernel(const unsigned int* __restrict__ H2B, const int* __restrict__ rowptr,
                         const int* __restrict__ col, const float* __restrict__ dinv,
                         const float* __restrict__ b2, float* __restrict__ out, int N){
  int i = blockIdx.x*blockDim.x + threadIdx.x;
  if (i >= N) return;
  float acc[10], acc2[10];
  #pragma unroll
  for (int c=0;c<10;c++){ acc[c] = 0.f; acc2[c] = 0.f; }
  int s = rowptr[i], e = rowptr[i+1];
  int j = s;
  for (; j+1 < e; j += 2){
    const unsigned int* hA = H2B + (size_t)col[j]*8;
    const unsigned int* hB = H2B + (size_t)col[j+1]*8;
    uint4 a = *(const uint4*)hA; unsigned a4 = hA[4];
    uint4 b = *(const uint4*)hB; unsigned b4 = hB[4];
    acc[0]+=b2f_lo(a.x); acc[1]+=b2f_hi(a.x); acc[2]+=b2f_lo(a.y); acc[3]+=b2f_hi(a.y);
    acc[4]+=b2f_lo(a.z); acc[5]+=b2f_hi(a.z); acc[6]+=b2f_lo(a.w); acc[7]+=b2f_hi(a.w);
    acc[8]+=b2f_lo(a4);  acc[9]+=b2f_hi(a4);
    acc2[0]+=b2f_lo(b.x); acc2[1]+=b2f_hi(b.x); acc2[2]+=b2f_lo(b.y); acc2[3]+=b2f_hi(b.y);
    acc2[4]+=b2f_lo(b.z); acc2[5]+=b2f_hi(b.z); acc2[6]+=b2f_lo(b.w); acc2[7]+=b2f_hi(b.w);
    acc2[8]+=b2f_lo(b4);  acc2[9]+=b2f_hi(b4);
  }
  if (j < e){
    const unsigned int* hA = H2B + (size_t)col[j]*8;
    uint4 a = *(const uint4*)hA; unsigned a4 = hA[4];
    acc[0]+=b2f_lo(a.x); acc[1]+=b2f_hi(a.x); acc[2]+=b2f_lo(a.y); acc[3]+=b2f_hi(a.y);
    acc[4]+=b2f_lo(a.z); acc[5]+=b2f_hi(a.z); acc[6]+=b2f_lo(a.w); acc[7]+=b2f_hi(a.w);
    acc[8]+=b2f_lo(a4);  acc[9]+=b2f_hi(a4);
  }
  float dv = dinv[i];
  #pragma unroll
  for (int f=0;f<10;f++) acc[f] = dv*(acc[f] + acc2[f]) + b2[f];
  float m = acc[0];
  #pragma unroll
  for (int f=1;f<10;f++) m = fmaxf(m, acc[f]);
  float sum = 0.f;
  #pragma unroll
  for (int f=0;f<10;f++) sum += expf(acc[f] - m);
  float lg = m + logf(sum);
  #pragma unroll
  for (int f=0;f<10;f++) out[(size_t)i*10 + f] = acc[f] - lg;
}

// ---------------- launch ----------------

extern "C" void kernel_launch(void* const* d_in, const int* in_sizes, int n_in,
                              void* d_out, int out_size, void* d_ws, size_t ws_size,
                              hipStream_t stream){
  const float* x    = (const float*)d_in[0];
  const int*   ei   = (const int*)d_in[1];
  const float* W1   = (const float*)d_in[2];
  const float* b1   = (const float*)d_in[3];
  const float* W2   = (const float*)d_in[4];
  const float* b2   = (const float*)d_in[5];
  float* out = (float*)d_out;

  const int N = in_sizes[0] / 256;   // 100000
  const int E = in_sizes[1] / 2;     // 1600000
  const int NNZ = E + N;
  const int* src = ei;
  const int* dst = ei + E;
  const int NB = (N + BKT - 1) >> BKT_BITS;   // 196
  const int WB = 128;                         // wcvt tail blocks

  char* ws = (char*)d_ws;
  size_t off = 0;
  auto alloc = [&](size_t bytes)->char*{
    char* p = ws + off;
    off = (off + bytes + 255) & ~(size_t)255;
    return p;
  };
  // zero region: bhist | bcur (single small memset)
  int*   zreg   = (int*)  alloc((size_t)(MAXNB*2)*4);
  int*   bhist  = zreg;
  int*   bcur   = zreg + MAXNB;
  float* dinv   = (float*)alloc((size_t)N*4);
  int*   rowptr = (int*)  alloc((size_t)(N+1)*4);
  unsigned int* bins = (unsigned int*)alloc((size_t)E*4);
  int*   col    = (int*)  alloc((size_t)NNZ*4);
  unsigned short* w1t = (unsigned short*)alloc((size_t)128*256*2);
  unsigned short* h1b = (unsigned short*)alloc((size_t)N*128*2);
  unsigned int*   r1b = (unsigned int*)  alloc((size_t)N*64*4);
  unsigned int*   h2b = (unsigned int*)  alloc((size_t)N*8*4);
  (void)ws_size;

  hipMemsetAsync(zreg, 0, (size_t)(MAXNB*2)*4, stream);

  const int NCB = (E + EB - 1) / EB;

  bhistA<<<NCB, 256, 0, stream>>>(dst, bhist, E, NB);
  binC<<<NCB, 256, 0, stream>>>(src, dst, bhist, bcur, bins, E, NB);
  bfill_all<<<NB + WB, 256, 0, stream>>>(bins, bhist, rowptr, dinv, col, W1, w1t, N, NB);

  gemm1_mfma<<<(N+127)/128, 256, 0, stream>>>(x, w1t, dinv, h1b, N);
  agg1_kernel<<<(N+3)/4, 256, 0, stream>>>(h1b, rowptr, col, dinv, b1, r1b, N);
  gemm2_kernel<<<(N+BLK-1)/BLK, BLK, 0, stream>>>(r1b, W2, dinv, h2b, N);
  agg2_softmax_kernel<<<(N+BLK-1)/BLK, BLK, 0, stream>>>(h2b, rowptr, col, dinv, b2, out, N);
}